// Round 8
// baseline (238.739 us; speedup 1.0000x reference)
//
#include <hip/hip_runtime.h>
#include <hip/hip_fp16.h>

typedef int v4i  __attribute__((ext_vector_type(4)));
typedef int v16i __attribute__((ext_vector_type(16)));
typedef const unsigned __attribute__((address_space(1)))* gas_t;
typedef unsigned __attribute__((address_space(3)))* las_t;

#define DIVFACTOR (1.0f / 16129.0f)

// pack low bytes of 4 int32 (sign-extended int8) into one dword
__device__ __forceinline__ unsigned pack4(int4 v) {
    return (unsigned)(v.x & 0xFF) | ((unsigned)(v.y & 0xFF) << 8) |
           ((unsigned)(v.z & 0xFF) << 16) | ((unsigned)v.w << 24);
}

__device__ __forceinline__ void gload16(const void* g, void* l) {
    __builtin_amdgcn_global_load_lds((gas_t)g, (las_t)l, 16, 0, 0);
}

// ---------------- pass 1: repack int32 -> half-tile-linear swizzled int8 ----------------
// Per matrix (16 MB, uint4 units): idx = (((p*32 + kt)*2 + h) << 10) + row*8 + (s ^ (row&7))
//   p = 256-row panel (16), kt = K-tile of 128 bytes (32), h = 128-row half (2),
//   row 0..127, s = 16B slot (8). One half-tile = 16 KB = exactly one GEMM staging unit.
// XOR slot swizzle spreads ds_read_b128 lanes uniformly over slots (8 lanes/slot = free).
__global__ __launch_bounds__(256) void pack_kernel(
    const int* __restrict__ x, const int* __restrict__ w, uint4* __restrict__ ws)
{
    const int u   = blockIdx.x * 256 + threadIdx.x;   // 0..2^20-1
    const int s   = u & 7;
    const int row = (u >> 3) & 127;
    const int h   = (u >> 10) & 1;
    const int kt  = (u >> 11) & 31;
    const int p   = u >> 16;
    const int* src = (blockIdx.y == 0) ? x : w;
    uint4* dst = ws + (size_t)blockIdx.y * 1048576;

    const int grow = p * 256 + h * 128 + row;
    const int4* sp = (const int4*)(src + (size_t)grow * 4096 + kt * 128 + s * 16);
    int4 s0 = sp[0], s1 = sp[1], s2 = sp[2], s3 = sp[3];
    uint4 d = make_uint4(pack4(s0), pack4(s1), pack4(s2), pack4(s3));
    dst[(((size_t)((p * 32 + kt) * 2 + h)) << 10) + row * 8 + (s ^ (row & 7))] = d;
}

// ---------------- pass 2: 256x256 8-phase i8 GEMM, 32x32x32 MFMA ----------------
// BK=128, 8 waves (2Mx4N), wave tile 128x64 = 4 m-blocks x 2 n-blocks of 32x32.
// LDS 128 KiB = 2 K-tile buffers. Same proven race-free schedule as round 5:
// buffer reads front-loaded into its first 2 phases; stages only after buffer death;
// counted vmcnt(4) at phases 3/7 (never 0 in steady state).
__global__ __launch_bounds__(512, 1) void i8gemm_8ph(
    const uint4* __restrict__ Ap, const uint4* __restrict__ Bp,
    const float* __restrict__ scale_x, const float* __restrict__ scale_w,
    const void* __restrict__ bias, float* __restrict__ out)
{
    __shared__ uint4 ldsq[8192];          // 128 KiB
    char* ldsb = (char*)ldsq;

    // T1: XCD-chunked swizzle (256 wgs, 8 XCDs, 32 contiguous tiles each)
    const int bid = blockIdx.x;
    const int swb = ((bid & 7) << 5) | (bid >> 3);
    const int bx  = swb & 15;             // N tile
    const int by  = swb >> 4;             // M tile

    const int t    = threadIdx.x;
    const int lane = t & 63;
    const int wid  = t >> 6;
    const int wr   = wid >> 2;            // 0..1 -> 128 out rows
    const int wc   = wid & 3;             // 0..3 -> 64 out cols
    const int al   = lane & 31;
    const int hi   = lane >> 5;

    // global panel bases (uint4): panel stride = 32 kt * 2 h * 1024 = 65536
    const uint4* aBase = Ap + (size_t)by * 65536 + t;   // + kt*2048 + h*1024 (+512)
    const uint4* bBase = Bp + (size_t)bx * 65536 + t;

    // LDS frag read offsets. A row = mb*32+al (half wr); B row = (wc&1)*64+nb*32+al (half wc>>1).
    // slot = (ks*2+hi) ^ (row&7); row&7 == al&7 for both A and B (block offsets are mult of 32).
    int swz[4];
    #pragma unroll
    for (int ks = 0; ks < 4; ++ks) swz[ks] = (((ks * 2 + hi) ^ (al & 7)) << 4);
    const int abase = wr * 16384 + al * 128;                              // + mb*4096 + swz[ks]
    const int bbase = 32768 + (wc >> 1) * 16384 + ((wc & 1) * 64 + al) * 128;  // + nb*4096 + swz[ks]

#define ARD(BUF,MB,KS) (*(const v4i*)(ldsb + (BUF)*65536 + abase + (MB)*4096 + swz[KS]))
#define BRD(BUF,NB,KS) (*(const v4i*)(ldsb + (BUF)*65536 + bbase + (NB)*4096 + swz[KS]))

#define STAGE(KT, MAT, HALF, BUF) do{ \
    const uint4* s_ = ((MAT) ? bBase : aBase) + (KT)*2048 + (HALF)*1024; \
    char* d_ = ldsb + (BUF)*65536 + (MAT)*32768 + (HALF)*16384 + t*16; \
    gload16((const void*)s_, (void*)d_); \
    gload16((const void*)(s_ + 512), (void*)(d_ + 8192)); \
}while(0)

#define BAR asm volatile("s_barrier" ::: "memory")

#define RD_B_A0(BUF) do{ \
    _Pragma("unroll") for (int nb_ = 0; nb_ < 2; ++nb_) \
        _Pragma("unroll") for (int ks_ = 0; ks_ < 4; ++ks_) bfr[nb_][ks_] = BRD(BUF,nb_,ks_); \
    _Pragma("unroll") for (int ks_ = 0; ks_ < 4; ++ks_) afr[0][ks_] = ARD(BUF,0,ks_); \
}while(0)

#define RD_A123(BUF) do{ \
    _Pragma("unroll") for (int mb_ = 1; mb_ < 4; ++mb_) \
        _Pragma("unroll") for (int ks_ = 0; ks_ < 4; ++ks_) afr[mb_][ks_] = ARD(BUF,mb_,ks_); \
}while(0)

#define CLUSTER(MB) do{ \
    __builtin_amdgcn_s_setprio(1); \
    _Pragma("unroll") for (int ks_ = 0; ks_ < 4; ++ks_) { \
        acc[MB][0] = __builtin_amdgcn_mfma_i32_32x32x32_i8(afr[MB][ks_], bfr[0][ks_], acc[MB][0], 0,0,0); \
        acc[MB][1] = __builtin_amdgcn_mfma_i32_32x32x32_i8(afr[MB][ks_], bfr[1][ks_], acc[MB][1], 0,0,0); } \
    __builtin_amdgcn_s_setprio(0); \
}while(0)

// One iteration = K-tiles KB (buf0, phases 0-3) and KB+1 (buf1, phases 4-7).
// Stage map: ph0,1 -> buf1 B0,B1 (kt KB+1); ph2,3,4,5 -> buf0 A0,A1,B0,B1 (kt KB+2);
// ph6,7 -> buf1 A0,A1 (kt KB+3). vmcnt(4) at ph3/ph7 = all but newest 2 half-tiles landed.
#define ITER(KB, STEADY) do{ \
    RD_B_A0(0);  STAGE((KB)+1,1,0,1); BAR; CLUSTER(0); BAR;                   /* ph0 */ \
    RD_A123(0);  STAGE((KB)+1,1,1,1); BAR; CLUSTER(1); BAR;                   /* ph1 */ \
    if (STEADY) STAGE((KB)+2,0,0,0); BAR; CLUSTER(2); BAR;                    /* ph2 */ \
    if (STEADY) { STAGE((KB)+2,0,1,0); asm volatile("s_waitcnt vmcnt(4)" ::: "memory"); } \
    else        { asm volatile("s_waitcnt vmcnt(0)" ::: "memory"); } \
    BAR; CLUSTER(3); BAR;                                                     /* ph3 */ \
    RD_B_A0(1);  if (STEADY) STAGE((KB)+2,1,0,0); BAR; CLUSTER(0); BAR;       /* ph4 */ \
    RD_A123(1);  if (STEADY) STAGE((KB)+2,1,1,0); BAR; CLUSTER(1); BAR;       /* ph5 */ \
    if (STEADY) STAGE((KB)+3,0,0,1); BAR; CLUSTER(2); BAR;                    /* ph6 */ \
    if (STEADY) { STAGE((KB)+3,0,1,1); asm volatile("s_waitcnt vmcnt(4)" ::: "memory"); } \
    BAR; CLUSTER(3); BAR;                                                     /* ph7 */ \
}while(0)

    v16i acc[4][2];
    #pragma unroll
    for (int mb = 0; mb < 4; ++mb)
        #pragma unroll
        for (int nb = 0; nb < 2; ++nb)
            #pragma unroll
            for (int q = 0; q < 16; ++q) acc[mb][nb][q] = 0;
    v4i afr[4][4], bfr[2][4];

    // prologue: kt0 all 4 halves -> buf0; kt1 A0,A1 -> buf1; wait kt0 (vmcnt(4): 12-4=8 oldest)
    STAGE(0,0,0,0); STAGE(0,0,1,0); STAGE(0,1,0,0); STAGE(0,1,1,0);
    STAGE(1,0,0,1); STAGE(1,0,1,1);
    asm volatile("s_waitcnt vmcnt(4)" ::: "memory");
    BAR;

    for (int i = 0; i < 15; ++i) { ITER(2 * i, 1); }
    ITER(30, 0);

#undef ITER
#undef CLUSTER
#undef RD_A123
#undef RD_B_A0
#undef BAR
#undef STAGE
#undef BRD
#undef ARD

    // ---- epilogue ----
    const float p0  = ((const float*)bias)[0];
    const float ap0 = fabsf(p0);
    const bool bias_is_f32 = (ap0 >= 1e-6f && ap0 <= 1.0f);

    float swv[2], bvv[2];
    #pragma unroll
    for (int nb = 0; nb < 2; ++nb) {
        int col = bx * 256 + wc * 64 + nb * 32 + al;
        swv[nb] = scale_w[col];
        bvv[nb] = bias_is_f32 ? ((const float*)bias)[col]
                              : __half2float(((const __half*)bias)[col]);
    }

    // 32x32 C/D mapping (m74/m101): col = lane&31, row = (reg&3) + 8*(reg>>2) + 4*(lane>>5)
    #pragma unroll
    for (int mb = 0; mb < 4; ++mb) {
        #pragma unroll
        for (int q = 0; q < 16; ++q) {
            int row = by * 256 + wr * 128 + mb * 32 + (q & 3) + 8 * (q >> 2) + 4 * hi;
            float sx_ = scale_x[row] * DIVFACTOR;
            #pragma unroll
            for (int nb = 0; nb < 2; ++nb) {
                int col = bx * 256 + wc * 64 + nb * 32 + al;
                float v = (float)acc[mb][nb][q] * sx_ * swv[nb] + bvv[nb];
                out[(size_t)row * 4096 + col] = __half2float(__float2half(v));
            }
        }
    }
}

// ---------------- fallback (round-1 fused kernel, used only if ws too small) ----------------
__global__ __launch_bounds__(256) void i8gemm_kernel(
    const int* __restrict__ x, const int* __restrict__ w,
    const float* __restrict__ scale_x, const float* __restrict__ scale_w,
    const void* __restrict__ bias, float* __restrict__ out)
{
    __shared__ int lds[4096];
    const int t = threadIdx.x, bx = blockIdx.x, by = blockIdx.y;
    const int lane = t & 63, wid = t >> 6, wr = wid >> 1, wc = wid & 1;
    const int th = t >> 4, tl = t & 15;
    const int* aptr = x + (size_t)(by * 128 + th) * 4096 + tl * 4;
    const int* bptr = w + (size_t)(bx * 128 + th) * 4096 + tl * 4;
    const int wbase = th * 16 + (tl ^ (((th >> 1) & 3) << 2));
    const int r = lane & 15, g = lane >> 4;
    const int sw4 = (r >> 1) & 3;
    const int a_rd = (wr * 64 + r) * 16 + ((g ^ sw4) << 2);
    const int b_rd = 2048 + (wc * 64 + r) * 16 + ((g ^ sw4) << 2);

    v4i acc[4][4];
    #pragma unroll
    for (int m = 0; m < 4; ++m)
        #pragma unroll
        for (int n = 0; n < 4; ++n) acc[m][n] = (v4i){0, 0, 0, 0};

    int4 va[8], vb[8];
    #pragma unroll
    for (int j = 0; j < 8; ++j) { va[j] = *(const int4*)(aptr + j * 65536); vb[j] = *(const int4*)(bptr + j * 65536); }

    for (int kt = 0; kt < 64; ++kt) {
        __syncthreads();
        #pragma unroll
        for (int j = 0; j < 8; ++j) {
            lds[wbase + j * 256]        = (int)pack4(va[j]);
            lds[2048 + wbase + j * 256] = (int)pack4(vb[j]);
        }
        __syncthreads();
        if (kt < 63) {
            const int* ap = aptr + (kt + 1) * 64;
            const int* bp = bptr + (kt + 1) * 64;
            #pragma unroll
            for (int j = 0; j < 8; ++j) { va[j] = *(const int4*)(ap + j * 65536); vb[j] = *(const int4*)(bp + j * 65536); }
        }
        v4i af[4], bf[4];
        #pragma unroll
        for (int m = 0; m < 4; ++m) af[m] = *(const v4i*)&lds[a_rd + m * 256];
        #pragma unroll
        for (int n = 0; n < 4; ++n) bf[n] = *(const v4i*)&lds[b_rd + n * 256];
        #pragma unroll
        for (int m = 0; m < 4; ++m)
            #pragma unroll
            for (int n = 0; n < 4; ++n)
                acc[m][n] = __builtin_amdgcn_mfma_i32_16x16x64_i8(af[m], bf[n], acc[m][n], 0, 0, 0);
    }

    const float p0 = ((const float*)bias)[0];
    const float ap0 = fabsf(p0);
    const bool bias_is_f32 = (ap0 >= 1e-6f && ap0 <= 1.0f);
    float sxv[4][4];
    #pragma unroll
    for (int m = 0; m < 4; ++m)
        #pragma unroll
        for (int q = 0; q < 4; ++q)
            sxv[m][q] = scale_x[by * 128 + wr * 64 + m * 16 + g * 4 + q] * DIVFACTOR;
    float swv[4], bvv[4];
    #pragma unroll
    for (int n = 0; n < 4; ++n) {
        int col = bx * 128 + wc * 64 + n * 16 + r;
        swv[n] = scale_w[col];
        bvv[n] = bias_is_f32 ? ((const float*)bias)[col] : __half2float(((const __half*)bias)[col]);
    }
    #pragma unroll
    for (int m = 0; m < 4; ++m)
        #pragma unroll
        for (int q = 0; q < 4; ++q) {
            int row = by * 128 + wr * 64 + m * 16 + g * 4 + q;
            float s = sxv[m][q];
            #pragma unroll
            for (int n = 0; n < 4; ++n) {
                int col = bx * 128 + wc * 64 + n * 16 + r;
                float v = (float)acc[m][n][q] * s * swv[n] + bvv[n];
                out[(size_t)row * 4096 + col] = __half2float(__float2half(v));
            }
        }
}

extern "C" void kernel_launch(void* const* d_in, const int* in_sizes, int n_in,
                              void* d_out, int out_size, void* d_ws, size_t ws_size,
                              hipStream_t stream) {
    const int*   x   = (const int*)d_in[0];
    const float* sx  = (const float*)d_in[1];
    const int*   w   = (const int*)d_in[2];
    const float* sw  = (const float*)d_in[3];
    const void*  bi  = d_in[4];
    float*       out = (float*)d_out;
    (void)in_sizes; (void)n_in; (void)out_size;

    if (ws_size >= (size_t)33554432) {
        uint4* ws = (uint4*)d_ws;
        hipLaunchKernelGGL(pack_kernel, dim3(4096, 2, 1), dim3(256, 1, 1), 0, stream, x, w, ws);
        hipLaunchKernelGGL(i8gemm_8ph, dim3(256, 1, 1), dim3(512, 1, 1), 0, stream,
                           ws, ws + 1048576, sx, sw, bi, out);
    } else {
        hipLaunchKernelGGL(i8gemm_kernel, dim3(32, 32, 1), dim3(256, 1, 1), 0, stream,
                           x, w, sx, sw, bi, out);
    }
}

// Round 9
// 231.387 us; speedup vs baseline: 1.0318x; 1.0318x over previous
//
#include <hip/hip_runtime.h>
#include <hip/hip_fp16.h>

typedef int v4i  __attribute__((ext_vector_type(4)));
typedef const unsigned __attribute__((address_space(1)))* gas_t;
typedef unsigned __attribute__((address_space(3)))* las_t;

#define DIVFACTOR (1.0f / 16129.0f)

// pack low bytes of 4 int32 (sign-extended int8) into one dword
__device__ __forceinline__ unsigned pack4(int4 v) {
    return (unsigned)(v.x & 0xFF) | ((unsigned)(v.y & 0xFF) << 8) |
           ((unsigned)(v.z & 0xFF) << 16) | ((unsigned)v.w << 24);
}

__device__ __forceinline__ void gload16(const void* g, void* l) {
    __builtin_amdgcn_global_load_lds((gas_t)g, (las_t)l, 16, 0, 0);
}

// ---------------- pass 1: repack int32 -> half-tile-linear swizzled int8 ----------------
// Per matrix (16 MB, uint4 units): idx = (((p*32 + kt)*2 + h) << 10) + row*8 + (s ^ (row&7))
//   p = 256-row panel (16), kt = K-tile of 128 bytes (32), h = 128-row half (2),
//   row 0..127, s = 16B slot (8). One half-tile = 16 KB = one GEMM staging unit.
__global__ __launch_bounds__(256) void pack_kernel(
    const int* __restrict__ x, const int* __restrict__ w, uint4* __restrict__ ws)
{
    const int u   = blockIdx.x * 256 + threadIdx.x;   // 0..2^20-1
    const int s   = u & 7;
    const int row = (u >> 3) & 127;
    const int h   = (u >> 10) & 1;
    const int kt  = (u >> 11) & 31;
    const int p   = u >> 16;
    const int* src = (blockIdx.y == 0) ? x : w;
    uint4* dst = ws + (size_t)blockIdx.y * 1048576;

    const int grow = p * 256 + h * 128 + row;
    const int4* sp = (const int4*)(src + (size_t)grow * 4096 + kt * 128 + s * 16);
    int4 s0 = sp[0], s1 = sp[1], s2 = sp[2], s3 = sp[3];
    uint4 d = make_uint4(pack4(s0), pack4(s1), pack4(s2), pack4(s3));
    dst[(((size_t)((p * 32 + kt) * 2 + h)) << 10) + row * 8 + (s ^ (row & 7))] = d;
}

// ---------------- pass 2: 256x256 8-phase i8 GEMM, 16x16x64 MFMA ----------------
// Round-5 skeleton + read-spreading: A-frag ds_reads JIT (4/phase ph0-3, 8/phase ph4-5),
// B-frags double-buffered in regs (bfrA/bfrB), their 8-read bursts issued AFTER the
// ph3/ph5 vmcnt+barrier in the MFMA shadow. Stage map: B stages ph0-3, A stages ph4-7.
// vmcnt(4) at ph3/ph5/ph7 (never 0 in steady state).
__global__ __launch_bounds__(512, 1) void i8gemm_8ph(
    const uint4* __restrict__ Ap, const uint4* __restrict__ Bp,
    const float* __restrict__ scale_x, const float* __restrict__ scale_w,
    const void* __restrict__ bias, float* __restrict__ out)
{
    __shared__ uint4 ldsq[8192];          // 128 KiB
    char* ldsb = (char*)ldsq;

    // T1: XCD-chunked swizzle (256 wgs, 8 XCDs, 32 contiguous tiles each)
    const int bid = blockIdx.x;
    const int swb = ((bid & 7) << 5) | (bid >> 3);
    const int bx  = swb & 15;             // N tile
    const int by  = swb >> 4;             // M tile

    const int t    = threadIdx.x;
    const int lane = t & 63;
    const int wid  = t >> 6;
    const int wr   = wid >> 2;            // 0..1 -> 128 out rows
    const int wc   = wid & 3;             // 0..3 -> 64 out cols
    const int r    = lane & 15;
    const int g    = lane >> 4;

    const uint4* aBase = Ap + (size_t)by * 65536 + t;   // + kt*2048 + h*1024 (+512)
    const uint4* bBase = Bp + (size_t)bx * 65536 + t;

    // fragment read byte offsets (round-5 verified, conflict-free)
    const int sl0 = ((g ^ (r & 7)) << 4);
    const int sl1 = (((4 + g) ^ (r & 7)) << 4);
    const int aoff0 = wr * 16384 + r * 128 + sl0;                       // + m*2048
    const int aoff1 = wr * 16384 + r * 128 + sl1;
    const int boff0 = 32768 + (wc >> 1) * 16384 + ((wc & 1) * 64 + r) * 128 + sl0;  // + n*2048
    const int boff1 = 32768 + (wc >> 1) * 16384 + ((wc & 1) * 64 + r) * 128 + sl1;

#define ARD(BUF,M,KS) (*(const v4i*)(ldsb + (BUF)*65536 + aoff##KS + (M)*2048))
#define BRD(BUF,N,KS) (*(const v4i*)(ldsb + (BUF)*65536 + boff##KS + (N)*2048))

#define STAGE(KT, MAT, HALF, BUF) do{ \
    const uint4* s_ = ((MAT) ? bBase : aBase) + (KT)*2048 + (HALF)*1024; \
    char* d_ = ldsb + (BUF)*65536 + (MAT)*32768 + (HALF)*16384 + t*16; \
    gload16((const void*)s_, (void*)d_); \
    gload16((const void*)(s_ + 512), (void*)(d_ + 8192)); \
}while(0)

#define BAR asm volatile("s_barrier" ::: "memory")
#define VM4 asm volatile("s_waitcnt vmcnt(4)" ::: "memory")
#define VM0 asm volatile("s_waitcnt vmcnt(0)" ::: "memory")
#define VM8 asm volatile("s_waitcnt vmcnt(8)" ::: "memory")

#define RD_A2(BUF,M0) do{ \
    afr[M0][0]   = ARD(BUF,M0,0);   afr[M0][1]   = ARD(BUF,M0,1); \
    afr[(M0)+1][0] = ARD(BUF,(M0)+1,0); afr[(M0)+1][1] = ARD(BUF,(M0)+1,1); \
}while(0)

#define RD_B8(BUF,ARR) do{ \
    _Pragma("unroll") for (int n_ = 0; n_ < 4; ++n_) { \
        ARR[n_][0] = BRD(BUF,n_,0); ARR[n_][1] = BRD(BUF,n_,1); } \
}while(0)

#define CLUSTER(ARR,MA,MB) do{ \
    __builtin_amdgcn_s_setprio(1); \
    _Pragma("unroll") for (int n_ = 0; n_ < 4; ++n_) { \
        acc[MA][n_] = __builtin_amdgcn_mfma_i32_16x16x64_i8(afr[MA][0], ARR[n_][0], acc[MA][n_], 0,0,0); \
        acc[MA][n_] = __builtin_amdgcn_mfma_i32_16x16x64_i8(afr[MA][1], ARR[n_][1], acc[MA][n_], 0,0,0); \
        acc[MB][n_] = __builtin_amdgcn_mfma_i32_16x16x64_i8(afr[MB][0], ARR[n_][0], acc[MB][n_], 0,0,0); \
        acc[MB][n_] = __builtin_amdgcn_mfma_i32_16x16x64_i8(afr[MB][1], ARR[n_][1], acc[MB][n_], 0,0,0); } \
    __builtin_amdgcn_s_setprio(0); \
}while(0)

// Iteration: kt=KB in buf0 (ph0-3, operands bfrA), kt=KB+1 in buf1 (ph4-7, bfrB).
// Stage map: ph0: b1.B0(KB+1)  ph1: b1.B1(KB+1)  ph2: b0.B0(KB+2)  ph3: b0.B1(KB+2)
//            ph4: b0.A0(KB+2)  ph5: b0.A1(KB+2)  ph6: b1.A0(KB+3)  ph7: b1.A1(KB+3)
// Lifetimes: b0.A read ph0-3 (stage ph4,5 OK); b1.A read ph4-5 (stage ph6,7 OK);
//            b0.B(KB) read prev ph5-post; b1.B(KB+1) read ph3-post.
#define ITER(KB, STEADY) do{ \
    RD_A2(0,0); STAGE((KB)+1,1,0,1); BAR; CLUSTER(bfrA,0,1); BAR;             /* ph0 */ \
    RD_A2(0,2); STAGE((KB)+1,1,1,1); BAR; CLUSTER(bfrA,2,3); BAR;             /* ph1 */ \
    RD_A2(0,4); if (STEADY) STAGE((KB)+2,1,0,0); BAR; CLUSTER(bfrA,4,5); BAR; /* ph2 */ \
    RD_A2(0,6); if (STEADY) { STAGE((KB)+2,1,1,0); VM4; } else { VM0; } \
    BAR; RD_B8(1,bfrB); CLUSTER(bfrA,6,7); BAR;                               /* ph3 */ \
    RD_A2(1,0); RD_A2(1,2); if (STEADY) STAGE((KB)+2,0,0,0); BAR; CLUSTER(bfrB,0,1); BAR; /* ph4 */ \
    RD_A2(1,4); RD_A2(1,6); if (STEADY) { STAGE((KB)+2,0,1,0); VM4; } \
    BAR; if (STEADY) RD_B8(0,bfrA); CLUSTER(bfrB,2,3); BAR;                   /* ph5 */ \
    if (STEADY) STAGE((KB)+3,0,0,1); BAR; CLUSTER(bfrB,4,5); BAR;             /* ph6 */ \
    if (STEADY) { STAGE((KB)+3,0,1,1); VM4; } BAR; CLUSTER(bfrB,6,7); BAR;    /* ph7 */ \
}while(0)

    v4i acc[8][4];
    #pragma unroll
    for (int m = 0; m < 8; ++m)
        #pragma unroll
        for (int n = 0; n < 4; ++n) acc[m][n] = (v4i){0, 0, 0, 0};
    v4i afr[8][2], bfrA[4][2], bfrB[4][2];

    // prologue: buf0 <- kt0 (B then A), buf1.A <- kt1. vmcnt(8): b0.B landed -> read bfrA;
    // vmcnt(4): b0.A landed (leaves b1.A, covered by iter0 ph3's vmcnt(4)).
    STAGE(0,1,0,0); STAGE(0,1,1,0);
    STAGE(0,0,0,0); STAGE(0,0,1,0);
    STAGE(1,0,0,1); STAGE(1,0,1,1);
    VM8; BAR;
    RD_B8(0,bfrA);
    VM4; BAR;

    for (int i = 0; i < 15; ++i) { ITER(2 * i, 1); }
    ITER(30, 0);

#undef ITER
#undef CLUSTER
#undef RD_B8
#undef RD_A2
#undef VM8
#undef VM0
#undef VM4
#undef BAR
#undef STAGE
#undef BRD
#undef ARD

    // ---- epilogue (round-5 verified 16x16 C/D mapping) ----
    const float p0  = ((const float*)bias)[0];
    const float ap0 = fabsf(p0);
    const bool bias_is_f32 = (ap0 >= 1e-6f && ap0 <= 1.0f);

    float swv[4], bvv[4];
    #pragma unroll
    for (int n = 0; n < 4; ++n) {
        int col = bx * 256 + wc * 64 + n * 16 + r;
        swv[n] = scale_w[col];
        bvv[n] = bias_is_f32 ? ((const float*)bias)[col]
                             : __half2float(((const __half*)bias)[col]);
    }

    #pragma unroll
    for (int m = 0; m < 8; ++m) {
        float sxr[4];
        #pragma unroll
        for (int q = 0; q < 4; ++q)
            sxr[q] = scale_x[by * 256 + wr * 128 + m * 16 + g * 4 + q] * DIVFACTOR;
        #pragma unroll
        for (int q = 0; q < 4; ++q) {
            int row = by * 256 + wr * 128 + m * 16 + g * 4 + q;
            #pragma unroll
            for (int n = 0; n < 4; ++n) {
                int col = bx * 256 + wc * 64 + n * 16 + r;
                float v = (float)acc[m][n][q] * sxr[q] * swv[n] + bvv[n];
                out[(size_t)row * 4096 + col] = __half2float(__float2half(v));
            }
        }
    }
}

// ---------------- fallback (round-1 fused kernel, used only if ws too small) ----------------
__global__ __launch_bounds__(256) void i8gemm_kernel(
    const int* __restrict__ x, const int* __restrict__ w,
    const float* __restrict__ scale_x, const float* __restrict__ scale_w,
    const void* __restrict__ bias, float* __restrict__ out)
{
    __shared__ int lds[4096];
    const int t = threadIdx.x, bx = blockIdx.x, by = blockIdx.y;
    const int lane = t & 63, wid = t >> 6, wr = wid >> 1, wc = wid & 1;
    const int th = t >> 4, tl = t & 15;
    const int* aptr = x + (size_t)(by * 128 + th) * 4096 + tl * 4;
    const int* bptr = w + (size_t)(bx * 128 + th) * 4096 + tl * 4;
    const int wbase = th * 16 + (tl ^ (((th >> 1) & 3) << 2));
    const int r = lane & 15, g = lane >> 4;
    const int sw4 = (r >> 1) & 3;
    const int a_rd = (wr * 64 + r) * 16 + ((g ^ sw4) << 2);
    const int b_rd = 2048 + (wc * 64 + r) * 16 + ((g ^ sw4) << 2);

    v4i acc[4][4];
    #pragma unroll
    for (int m = 0; m < 4; ++m)
        #pragma unroll
        for (int n = 0; n < 4; ++n) acc[m][n] = (v4i){0, 0, 0, 0};

    int4 va[8], vb[8];
    #pragma unroll
    for (int j = 0; j < 8; ++j) { va[j] = *(const int4*)(aptr + j * 65536); vb[j] = *(const int4*)(bptr + j * 65536); }

    for (int kt = 0; kt < 64; ++kt) {
        __syncthreads();
        #pragma unroll
        for (int j = 0; j < 8; ++j) {
            lds[wbase + j * 256]        = (int)pack4(va[j]);
            lds[2048 + wbase + j * 256] = (int)pack4(vb[j]);
        }
        __syncthreads();
        if (kt < 63) {
            const int* ap = aptr + (kt + 1) * 64;
            const int* bp = bptr + (kt + 1) * 64;
            #pragma unroll
            for (int j = 0; j < 8; ++j) { va[j] = *(const int4*)(ap + j * 65536); vb[j] = *(const int4*)(bp + j * 65536); }
        }
        v4i af[4], bf[4];
        #pragma unroll
        for (int m = 0; m < 4; ++m) af[m] = *(const v4i*)&lds[a_rd + m * 256];
        #pragma unroll
        for (int n = 0; n < 4; ++n) bf[n] = *(const v4i*)&lds[b_rd + n * 256];
        #pragma unroll
        for (int m = 0; m < 4; ++m)
            #pragma unroll
            for (int n = 0; n < 4; ++n)
                acc[m][n] = __builtin_amdgcn_mfma_i32_16x16x64_i8(af[m], bf[n], acc[m][n], 0, 0, 0);
    }

    const float p0 = ((const float*)bias)[0];
    const float ap0 = fabsf(p0);
    const bool bias_is_f32 = (ap0 >= 1e-6f && ap0 <= 1.0f);
    float sxv[4][4];
    #pragma unroll
    for (int m = 0; m < 4; ++m)
        #pragma unroll
        for (int q = 0; q < 4; ++q)
            sxv[m][q] = scale_x[by * 128 + wr * 64 + m * 16 + g * 4 + q] * DIVFACTOR;
    float swv[4], bvv[4];
    #pragma unroll
    for (int n = 0; n < 4; ++n) {
        int col = bx * 128 + wc * 64 + n * 16 + r;
        swv[n] = scale_w[col];
        bvv[n] = bias_is_f32 ? ((const float*)bias)[col] : __half2float(((const __half*)bias)[col]);
    }
    #pragma unroll
    for (int m = 0; m < 4; ++m)
        #pragma unroll
        for (int q = 0; q < 4; ++q) {
            int row = by * 128 + wr * 64 + m * 16 + g * 4 + q;
            float s = sxv[m][q];
            #pragma unroll
            for (int n = 0; n < 4; ++n) {
                int col = bx * 128 + wc * 64 + n * 16 + r;
                float v = (float)acc[m][n][q] * s * swv[n] + bvv[n];
                out[(size_t)row * 4096 + col] = __half2float(__float2half(v));
            }
        }
}

extern "C" void kernel_launch(void* const* d_in, const int* in_sizes, int n_in,
                              void* d_out, int out_size, void* d_ws, size_t ws_size,
                              hipStream_t stream) {
    const int*   x   = (const int*)d_in[0];
    const float* sx  = (const float*)d_in[1];
    const int*   w   = (const int*)d_in[2];
    const float* sw  = (const float*)d_in[3];
    const void*  bi  = d_in[4];
    float*       out = (float*)d_out;
    (void)in_sizes; (void)n_in; (void)out_size;

    if (ws_size >= (size_t)33554432) {
        uint4* ws = (uint4*)d_ws;
        hipLaunchKernelGGL(pack_kernel, dim3(4096, 2, 1), dim3(256, 1, 1), 0, stream, x, w, ws);
        hipLaunchKernelGGL(i8gemm_8ph, dim3(256, 1, 1), dim3(512, 1, 1), 0, stream,
                           ws, ws + 1048576, sx, sw, bi, out);
    } else {
        hipLaunchKernelGGL(i8gemm_kernel, dim3(32, 32, 1), dim3(256, 1, 1), 0, stream,
                           x, w, sx, sw, bi, out);
    }
}